// Round 4
// baseline (262.294 us; speedup 1.0000x reference)
//
#include <hip/hip_runtime.h>
#include <hip/hip_bf16.h>

#define IN_DIM 256
#define NH 4
#define DQK 8
#define ATH 64
#define NB 2
#define NSP 4096  // 64*64
#define LOG2E 1.44269504088896f

typedef __attribute__((ext_vector_type(8))) short short8;
typedef __attribute__((ext_vector_type(16))) float f32x16;

// ws byte layout:
//   Q_OFF : q rows bf16 [8 bh][4096 n][8d]                       512 KB
//   K_OFF : k rows bf16 [8 bh][4096 m][8d] (pre-scaled log2e)    512 KB
//   VF_OFF: v B-frags bf16 [8 bh][128 T][2 c2][64 lane][8j]      2 MB
//           (lane = 32*h2 + e; elem j -> n = 32T+16c2+8h2+j, col e; e=8 ones)
//   P_OFF : partials f32 [8 bh][128 mt][4 nq][18 slot][16 r]     ~4.7 MB
//   C_OFF : completion counters int[8 bh][128 mt]                4 KB
#define Q_OFF 0u
#define K_OFF (512u * 1024u)
#define VF_OFF (1024u * 1024u)
#define P_OFF (3u * 1024u * 1024u)
#define C_OFF (8u * 1024u * 1024u)

__device__ __forceinline__ float fast_exp2(float x) {
#if __has_builtin(__builtin_amdgcn_exp2f)
    return __builtin_amdgcn_exp2f(x);
#else
    return exp2f(x);
#endif
}

// round-to-nearest-even fp32->bf16 (finite inputs only)
__device__ __forceinline__ unsigned bf_rne(float f) {
    unsigned u = __float_as_uint(f);
    u += 0x7FFFu + ((u >> 16) & 1u);
    return u >> 16;
}
__device__ __forceinline__ unsigned pack2bf(float a, float b) {
    return bf_rne(a) | (bf_rne(b) << 16);
}
// truncation pack (softmax P only: truncation bias cancels in P/sum(P)).
// v_perm_b32: D bytes = [a.b2, a.b3, b.b2, b.b3] -> sel 0x07060302 (S1=a, S0=b)
__device__ __forceinline__ unsigned pack2bf_tr(float a, float b) {
#if __has_builtin(__builtin_amdgcn_perm)
    return __builtin_amdgcn_perm(__float_as_uint(b), __float_as_uint(a), 0x07060302u);
#else
    return (__float_as_uint(a) >> 16) | (__float_as_uint(b) & 0xFFFF0000u);
#endif
}

// ---------------------------------------------------------------------------
// K1: qkv as one MFMA GEMM. D[96,4096] = Wcat[96,256] x[256,4096] per b.
// Rows R: h = R/24, sel = (R%24)/8 (0=q,1=k,2=v), d = R%8.
// grid (128 n-tiles, 3 m-tiles, 2 b) = 768 waves, 16 MFMAs each.
// Epilogue: +bias, k*log2e, xor-32 repack. q/k stored as coalesced 16B rows;
// v scattered directly into PV B-frag layout (incl. ones col e=8).
// Also zeroes the completion counters for K2 (block 0,0,0).
// ---------------------------------------------------------------------------
__global__ __launch_bounds__(64) void qkv_gemm(
    const float* __restrict__ x,
    const float* __restrict__ Wq, const float* __restrict__ bq,
    const float* __restrict__ Wk, const float* __restrict__ bk,
    const float* __restrict__ Wv, const float* __restrict__ bv,
    unsigned char* __restrict__ ws)
{
    const int lane = threadIdx.x;
    const int nt = blockIdx.x;   // 0..127
    const int mt = blockIdx.y;   // 0..2
    const int b  = blockIdx.z;   // 0..1
    const int col = lane & 31;
    const int hp  = lane >> 5;

    if (nt == 0 && mt == 0 && b == 0) {  // zero K2's counters (K2 runs after)
        int* cnt = (int*)(ws + C_OFF);
#pragma unroll
        for (int i = 0; i < 16; ++i) cnt[i * 64 + lane] = 0;
    }

    // this lane's A-row of Wcat
    const int R = mt * 32 + col;
    const int h = R / 24;
    const int r24 = R % 24;
    const int sel = r24 >> 3;
    const int dd = r24 & 7;
    const float* Wsel = (sel == 0) ? Wq : (sel == 1) ? Wk : Wv;
    const float* wrow = Wsel + (h * DQK + dd) * IN_DIM;

    // x column base: c = kt*16 + hp*8 + j, n = nt*32 + col
    const float* xb = x + (size_t)b * IN_DIM * NSP + (size_t)(hp * 8) * NSP + nt * 32 + col;

    union U4 { uint4 u; short8 s; };
    f32x16 acc = {};

#pragma unroll
    for (int kt = 0; kt < 16; ++kt) {
        const float4 wa = *(const float4*)(wrow + kt * 16 + hp * 8);
        const float4 wb = *(const float4*)(wrow + kt * 16 + hp * 8 + 4);
        U4 af;
        af.u.x = pack2bf(wa.x, wa.y);
        af.u.y = pack2bf(wa.z, wa.w);
        af.u.z = pack2bf(wb.x, wb.y);
        af.u.w = pack2bf(wb.z, wb.w);

        float xv[8];
#pragma unroll
        for (int j = 0; j < 8; ++j) xv[j] = xb[(size_t)(kt * 16 + j) * NSP];
        U4 bfm;
        bfm.u.x = pack2bf(xv[0], xv[1]);
        bfm.u.y = pack2bf(xv[2], xv[3]);
        bfm.u.z = pack2bf(xv[4], xv[5]);
        bfm.u.w = pack2bf(xv[6], xv[7]);

        acc = __builtin_amdgcn_mfma_f32_32x32x16_bf16(af.s, bfm.s, acc, 0, 0, 0);
    }

    // epilogue: rows m = (reg&3) + 8*(reg>>2) + 4*hp. Row-group g (m=8g..8g+7)
    // = regs 4g..4g+3; one (h,sel) per group. Pair groups, xor-32 exchange so
    // hp0 holds group gA's full 8-d row, hp1 holds gB's.
    const int n = nt * 32 + col;
#pragma unroll
    for (int p = 0; p < 2; ++p) {
        const int gA = 2 * p, gB = 2 * p + 1;
        const int RA = mt * 32 + 8 * gA, RB = mt * 32 + 8 * gB;
        const int hA = RA / 24, hB = RB / 24;
        const int selA = (RA % 24) >> 3, selB = (RB % 24) >> 3;
        const float* bsA = (selA == 0) ? bq : (selA == 1) ? bk : bv;
        const float* bsB = (selB == 0) ? bq : (selB == 1) ? bk : bv;
        const float scA = (selA == 1) ? LOG2E : 1.0f;
        const float scB = (selB == 1) ? LOG2E : 1.0f;

        float vA[4], vB[4];
#pragma unroll
        for (int j = 0; j < 4; ++j) {
            vA[j] = (acc[4 * gA + j] + bsA[hA * DQK + 4 * hp + j]) * scA;
            vB[j] = (acc[4 * gB + j] + bsB[hB * DQK + 4 * hp + j]) * scB;
        }
        const unsigned PA0 = pack2bf(vA[0], vA[1]), PA1 = pack2bf(vA[2], vA[3]);
        const unsigned PB0 = pack2bf(vB[0], vB[1]), PB1 = pack2bf(vB[2], vB[3]);

        const int s0 = hp ? (int)PA0 : (int)PB0;
        const int s1 = hp ? (int)PA1 : (int)PB1;
        const unsigned r0 = (unsigned)__shfl_xor(s0, 32, 64);
        const unsigned r1 = (unsigned)__shfl_xor(s1, 32, 64);

        const uint4 row = hp ? make_uint4(r0, r1, PB0, PB1)
                             : make_uint4(PA0, PA1, r0, r1);

        // this lane now holds the full row of group gX = (hp ? gB : gA)
        const int selX = hp ? selB : selA;
        const int hX = hp ? hB : hA;
        const int bhX = b * NH + hX;

        if (selX == 2) {
            // scatter v row into PV B-frag layout + ones col e=8
            unsigned char* dst = ws + VF_OFF + (size_t)bhX * 262144u +
                (size_t)((nt * 2 + ((col >> 4) & 1)) * 64 + 32 * ((col >> 3) & 1)) * 16 +
                (col & 7) * 2;
            *(unsigned short*)(dst + 0 * 16) = (unsigned short)(row.x);
            *(unsigned short*)(dst + 1 * 16) = (unsigned short)(row.x >> 16);
            *(unsigned short*)(dst + 2 * 16) = (unsigned short)(row.y);
            *(unsigned short*)(dst + 3 * 16) = (unsigned short)(row.y >> 16);
            *(unsigned short*)(dst + 4 * 16) = (unsigned short)(row.z);
            *(unsigned short*)(dst + 5 * 16) = (unsigned short)(row.z >> 16);
            *(unsigned short*)(dst + 6 * 16) = (unsigned short)(row.w);
            *(unsigned short*)(dst + 7 * 16) = (unsigned short)(row.w >> 16);
            *(unsigned short*)(dst + 8 * 16) = 0x3F80;  // bf16 1.0
        } else {
            unsigned char* d = ws + ((selX == 0) ? Q_OFF : K_OFF) +
                               ((size_t)bhX * NSP + n) * 16;
            *(uint4*)d = row;
        }
    }
}

// ---------------------------------------------------------------------------
// K2: MFMA flash attention (transposed softmax) + fused last-block epilogue.
// 1 wave per (m-tile, bh, nq): grid (128, 8, 4). Main loop barrier/LDS-free.
// The 4th finisher per (bh,mt) reduces the 4 n-quarter partials and does
// Wo + bias + gamma + residual writeout for its 32 columns.
// ---------------------------------------------------------------------------
__global__ __launch_bounds__(64, 4) void attn_fused(
    unsigned char* __restrict__ ws,
    const float* __restrict__ x,
    const float* __restrict__ Wo, const float* __restrict__ bo,
    const float* __restrict__ gamma,
    float* __restrict__ out)
{
    const int lane = threadIdx.x;
    const int mt = blockIdx.x;   // 0..127
    const int bh = blockIdx.y;   // 0..7
    const int nq = blockIdx.z;   // 0..3
    const int e = lane & 31;
    const int hp = lane >> 5;

    union U4 { uint4 u; short8 s; };
    const uint4 zero4 = make_uint4(0, 0, 0, 0);

    U4 kf;
    kf.u = (hp == 0)
        ? *(const uint4*)(ws + K_OFF + ((size_t)bh * NSP + mt * 32 + e) * 16)
        : zero4;

    const uint4* qrows = (const uint4*)(ws + Q_OFF + (size_t)bh * NSP * 16);
    const uint4* vfr = (const uint4*)(ws + VF_OFF + (size_t)bh * 262144u);

    f32x16 acc = {};
    const f32x16 zc = {};

    const int nt0 = nq * 32;
    U4 qf_n, vf0_n, vf1_n;
    qf_n.u = (hp == 0) ? qrows[nt0 * 32 + e] : zero4;
    vf0_n.u = vfr[(nt0 * 2 + 0) * 64 + lane];
    vf1_n.u = vfr[(nt0 * 2 + 1) * 64 + lane];

    for (int t = 0; t < 32; ++t) {
        U4 qf = qf_n, vf0 = vf0_n, vf1 = vf1_n;
        if (t < 31) {  // software prefetch next tile
            const int nt = nt0 + t + 1;
            qf_n.u = (hp == 0) ? qrows[nt * 32 + e] : zero4;
            vf0_n.u = vfr[(nt * 2 + 0) * 64 + lane];
            vf1_n.u = vfr[(nt * 2 + 1) * 64 + lane];
        }

        // S^T[n,m]: lane holds col m, 16 rows n
        f32x16 S = __builtin_amdgcn_mfma_f32_32x32x16_bf16(qf.s, kf.s, zc, 0, 0, 0);

        // exp2 (k pre-scaled by log2e) + truncation-pack to bf16 (v_perm)
        unsigned Qd[8];
#pragma unroll
        for (int i = 0; i < 8; ++i) {
            const float a = fast_exp2(S[2 * i]);
            const float b2 = fast_exp2(S[2 * i + 1]);
            Qd[i] = pack2bf_tr(a, b2);
        }

        // xor-32 exchange: build A-layout frags (rows m, k=n)
        const int sA0 = hp ? Qd[0] : Qd[2];
        const int sA1 = hp ? Qd[1] : Qd[3];
        const int rA0 = __shfl_xor(sA0, 32, 64);
        const int rA1 = __shfl_xor(sA1, 32, 64);
        const int sB0 = hp ? Qd[4] : Qd[6];
        const int sB1 = hp ? Qd[5] : Qd[7];
        const int rB0 = __shfl_xor(sB0, 32, 64);
        const int rB1 = __shfl_xor(sB1, 32, 64);

        U4 f0, f1;
        f0.u = hp ? make_uint4(rA0, rA1, Qd[2], Qd[3])
                  : make_uint4(Qd[0], Qd[1], rA0, rA1);
        f1.u = hp ? make_uint4(rB0, rB1, Qd[6], Qd[7])
                  : make_uint4(Qd[4], Qd[5], rB0, rB1);

        acc = __builtin_amdgcn_mfma_f32_32x32x16_bf16(f0.s, vf0.s, acc, 0, 0, 0);
        acc = __builtin_amdgcn_mfma_f32_32x32x16_bf16(f1.s, vf1.s, acc, 0, 0, 0);
    }

    // store partial (cols e<=8: 8 o-channels + l at e=8), 4x float4 per lane
    float* P = (float*)(ws + P_OFF);
    if (e <= 8) {
        float* pp = P + ((((size_t)bh * 128 + mt) * 4 + nq) * 18 + hp * 9 + e) * 16;
        *(float4*)(pp + 0)  = make_float4(acc[0], acc[1], acc[2], acc[3]);
        *(float4*)(pp + 4)  = make_float4(acc[4], acc[5], acc[6], acc[7]);
        *(float4*)(pp + 8)  = make_float4(acc[8], acc[9], acc[10], acc[11]);
        *(float4*)(pp + 12) = make_float4(acc[12], acc[13], acc[14], acc[15]);
    }

    // last-arriving block per (bh,mt) does the epilogue
    __threadfence();
    __shared__ int s_old;
    if (lane == 0) {
        int* cnt = (int*)(ws + C_OFF) + bh * 128 + mt;
        s_old = atomicAdd(cnt, 1);
    }
    __syncthreads();
    if (s_old != 3) return;
    __threadfence();

    __shared__ float sO[32 * 9];
    const float* Pb = P + ((size_t)bh * 128 + mt) * 4 * 288;
    for (int idx = lane; idx < 288; idx += 64) {
        const int slot = idx >> 4, r = idx & 15;
        const int hp2 = slot / 9, e2 = slot - hp2 * 9;
        const int m = (r & 3) + 8 * (r >> 2) + 4 * hp2;
        sO[m * 9 + e2] = Pb[idx] + Pb[288 + idx] + Pb[576 + idx] + Pb[864 + idx];
    }
    __syncthreads();

    const int h = bh & (NH - 1);
    const int b = bh >> 2;
    const int m = lane & 31;
    const float rl = 1.0f / sO[m * 9 + 8];
    float od[DQK];
#pragma unroll
    for (int d = 0; d < DQK; ++d) od[d] = sO[m * 9 + d] * rl;

    const float g = gamma[h];
    const int mg = mt * 32 + m;
#pragma unroll 8
    for (int i = 0; i < 32; ++i) {
        const int eo = hp * 32 + i;
        const float* wo = Wo + (h * ATH + eo) * DQK;
        float y = bo[h * ATH + eo];
#pragma unroll
        for (int d = 0; d < DQK; ++d) y = fmaf(wo[d], od[d], y);
        const size_t oi = ((size_t)(b * IN_DIM) + h * ATH + eo) * NSP + mg;
        out[oi] = fmaf(g, y, x[oi]);
    }
}

extern "C" void kernel_launch(void* const* d_in, const int* in_sizes, int n_in,
                              void* d_out, int out_size, void* d_ws, size_t ws_size,
                              hipStream_t stream)
{
    const float* x = (const float*)d_in[0];
    const float* Wq = (const float*)d_in[1];
    const float* bq = (const float*)d_in[2];
    const float* Wk = (const float*)d_in[3];
    const float* bk = (const float*)d_in[4];
    const float* Wv = (const float*)d_in[5];
    const float* bv = (const float*)d_in[6];
    const float* Wo = (const float*)d_in[7];
    const float* bo = (const float*)d_in[8];
    const float* gamma = (const float*)d_in[9];
    float* out = (float*)d_out;
    unsigned char* ws = (unsigned char*)d_ws;  // uses ~8 MB

    qkv_gemm<<<dim3(128, 3, NB), 64, 0, stream>>>(
        x, Wq, bq, Wk, bk, Wv, bv, ws);
    attn_fused<<<dim3(128, NB * NH, 4), 64, 0, stream>>>(
        ws, x, Wo, bo, gamma, out);
}

// Round 5
// 117.363 us; speedup vs baseline: 2.2349x; 2.2349x over previous
//
#include <hip/hip_runtime.h>
#include <hip/hip_bf16.h>

#define IN_DIM 256
#define NH 4
#define DQK 8
#define ATH 64
#define NB 2
#define NSP 4096  // 64*64
#define LOG2E 1.44269504088896f

typedef __attribute__((ext_vector_type(8))) short short8;
typedef __attribute__((ext_vector_type(16))) float f32x16;

// ws byte layout:
//   Q_OFF : q rows bf16 [8 bh][4096 n][8d]                       512 KB
//   K_OFF : k rows bf16 [8 bh][4096 m][8d] (pre-scaled log2e)    512 KB
//   VF_OFF: v B-frags bf16 [8 bh][128 T][2 c2][64 lane][8j]      2 MB
//           (lane = 32*h2 + e; elem j -> n = 32T+16c2+8h2+j, col e; e=8 ones)
//   P_OFF : partials f32 [8 bh][128 mt][4 nq][18 slot][16 r]     ~4.7 MB
// NOTE (round-4 lesson): no cross-block fences/atomics anywhere — an
// all-blocks device-scope __threadfence() (buffer_wbl2) cost ~180 us.
// The kernel boundary is the cross-XCD release point.
#define Q_OFF 0u
#define K_OFF (512u * 1024u)
#define VF_OFF (1024u * 1024u)
#define P_OFF (3u * 1024u * 1024u)

__device__ __forceinline__ float fast_exp2(float x) {
#if __has_builtin(__builtin_amdgcn_exp2f)
    return __builtin_amdgcn_exp2f(x);
#else
    return exp2f(x);
#endif
}

// round-to-nearest-even fp32->bf16 (finite inputs only)
__device__ __forceinline__ unsigned bf_rne(float f) {
    unsigned u = __float_as_uint(f);
    u += 0x7FFFu + ((u >> 16) & 1u);
    return u >> 16;
}
__device__ __forceinline__ unsigned pack2bf(float a, float b) {
    return bf_rne(a) | (bf_rne(b) << 16);
}
// truncation pack (softmax P only: truncation bias cancels in P/sum(P)).
// v_perm_b32: D bytes = [b.b2, b.b3 | a.b2, a.b3] -> sel 0x07060302 (S1=a, S0=b)
__device__ __forceinline__ unsigned pack2bf_tr(float a, float b) {
#if __has_builtin(__builtin_amdgcn_perm)
    return __builtin_amdgcn_perm(__float_as_uint(b), __float_as_uint(a), 0x07060302u);
#else
    return (__float_as_uint(a) >> 16) | (__float_as_uint(b) & 0xFFFF0000u);
#endif
}

// ---------------------------------------------------------------------------
// K1: qkv as one MFMA GEMM. D[96,4096] = Wcat[96,256] x[256,4096] per b.
// Rows R: h = R/24, sel = (R%24)/8 (0=q,1=k,2=v), d = R%8.
// grid (128 n-tiles, 3 m-tiles, 2 b) = 768 waves, 16 MFMAs each.
// Epilogue: +bias, k*log2e, xor-32 repack. q/k stored as coalesced 16B rows;
// v scattered directly into PV B-frag layout (incl. ones col e=8).
// ---------------------------------------------------------------------------
__global__ __launch_bounds__(64) void qkv_gemm(
    const float* __restrict__ x,
    const float* __restrict__ Wq, const float* __restrict__ bq,
    const float* __restrict__ Wk, const float* __restrict__ bk,
    const float* __restrict__ Wv, const float* __restrict__ bv,
    unsigned char* __restrict__ ws)
{
    const int lane = threadIdx.x;
    const int nt = blockIdx.x;   // 0..127
    const int mt = blockIdx.y;   // 0..2
    const int b  = blockIdx.z;   // 0..1
    const int col = lane & 31;
    const int hp  = lane >> 5;

    // this lane's A-row of Wcat
    const int R = mt * 32 + col;
    const int h = R / 24;
    const int r24 = R % 24;
    const int sel = r24 >> 3;
    const int dd = r24 & 7;
    const float* Wsel = (sel == 0) ? Wq : (sel == 1) ? Wk : Wv;
    const float* wrow = Wsel + (h * DQK + dd) * IN_DIM;

    // x column base: c = kt*16 + hp*8 + j, n = nt*32 + col
    const float* xb = x + (size_t)b * IN_DIM * NSP + (size_t)(hp * 8) * NSP + nt * 32 + col;

    union U4 { uint4 u; short8 s; };
    f32x16 acc = {};

#pragma unroll
    for (int kt = 0; kt < 16; ++kt) {
        const float4 wa = *(const float4*)(wrow + kt * 16 + hp * 8);
        const float4 wb = *(const float4*)(wrow + kt * 16 + hp * 8 + 4);
        U4 af;
        af.u.x = pack2bf(wa.x, wa.y);
        af.u.y = pack2bf(wa.z, wa.w);
        af.u.z = pack2bf(wb.x, wb.y);
        af.u.w = pack2bf(wb.z, wb.w);

        float xv[8];
#pragma unroll
        for (int j = 0; j < 8; ++j) xv[j] = xb[(size_t)(kt * 16 + j) * NSP];
        U4 bfm;
        bfm.u.x = pack2bf(xv[0], xv[1]);
        bfm.u.y = pack2bf(xv[2], xv[3]);
        bfm.u.z = pack2bf(xv[4], xv[5]);
        bfm.u.w = pack2bf(xv[6], xv[7]);

        acc = __builtin_amdgcn_mfma_f32_32x32x16_bf16(af.s, bfm.s, acc, 0, 0, 0);
    }

    // epilogue: rows m = (reg&3) + 8*(reg>>2) + 4*hp. Row-group g (m=8g..8g+7)
    // = regs 4g..4g+3; one (h,sel) per group. Pair groups, xor-32 exchange so
    // hp0 holds group gA's full 8-d row, hp1 holds gB's.
    const int n = nt * 32 + col;
#pragma unroll
    for (int p = 0; p < 2; ++p) {
        const int gA = 2 * p, gB = 2 * p + 1;
        const int RA = mt * 32 + 8 * gA, RB = mt * 32 + 8 * gB;
        const int hA = RA / 24, hB = RB / 24;
        const int selA = (RA % 24) >> 3, selB = (RB % 24) >> 3;
        const float* bsA = (selA == 0) ? bq : (selA == 1) ? bk : bv;
        const float* bsB = (selB == 0) ? bq : (selB == 1) ? bk : bv;
        const float scA = (selA == 1) ? LOG2E : 1.0f;
        const float scB = (selB == 1) ? LOG2E : 1.0f;

        float vA[4], vB[4];
#pragma unroll
        for (int j = 0; j < 4; ++j) {
            vA[j] = (acc[4 * gA + j] + bsA[hA * DQK + 4 * hp + j]) * scA;
            vB[j] = (acc[4 * gB + j] + bsB[hB * DQK + 4 * hp + j]) * scB;
        }
        const unsigned PA0 = pack2bf(vA[0], vA[1]), PA1 = pack2bf(vA[2], vA[3]);
        const unsigned PB0 = pack2bf(vB[0], vB[1]), PB1 = pack2bf(vB[2], vB[3]);

        const int s0 = hp ? (int)PA0 : (int)PB0;
        const int s1 = hp ? (int)PA1 : (int)PB1;
        const unsigned r0 = (unsigned)__shfl_xor(s0, 32, 64);
        const unsigned r1 = (unsigned)__shfl_xor(s1, 32, 64);

        const uint4 row = hp ? make_uint4(r0, r1, PB0, PB1)
                             : make_uint4(PA0, PA1, r0, r1);

        // this lane now holds the full row of group gX = (hp ? gB : gA)
        const int selX = hp ? selB : selA;
        const int hX = hp ? hB : hA;
        const int bhX = b * NH + hX;

        if (selX == 2) {
            // scatter v row into PV B-frag layout + ones col e=8
            unsigned char* dst = ws + VF_OFF + (size_t)bhX * 262144u +
                (size_t)((nt * 2 + ((col >> 4) & 1)) * 64 + 32 * ((col >> 3) & 1)) * 16 +
                (col & 7) * 2;
            *(unsigned short*)(dst + 0 * 16) = (unsigned short)(row.x);
            *(unsigned short*)(dst + 1 * 16) = (unsigned short)(row.x >> 16);
            *(unsigned short*)(dst + 2 * 16) = (unsigned short)(row.y);
            *(unsigned short*)(dst + 3 * 16) = (unsigned short)(row.y >> 16);
            *(unsigned short*)(dst + 4 * 16) = (unsigned short)(row.z);
            *(unsigned short*)(dst + 5 * 16) = (unsigned short)(row.z >> 16);
            *(unsigned short*)(dst + 6 * 16) = (unsigned short)(row.w);
            *(unsigned short*)(dst + 7 * 16) = (unsigned short)(row.w >> 16);
            *(unsigned short*)(dst + 8 * 16) = 0x3F80;  // bf16 1.0
        } else {
            unsigned char* d = ws + ((selX == 0) ? Q_OFF : K_OFF) +
                               ((size_t)bhX * NSP + n) * 16;
            *(uint4*)d = row;
        }
    }
}

// ---------------------------------------------------------------------------
// K2: MFMA flash attention (transposed softmax), partial over n-quarters.
// 1 wave per (m-tile, bh, nq): grid (128, 8, 4) = 4096 waves = 4/SIMD.
// Barrier-free, LDS-free, fence-free (cross-block reduce happens in K3;
// the kernel boundary provides the device-wide release).
// ---------------------------------------------------------------------------
__global__ __launch_bounds__(64, 4) void attn_partial(unsigned char* __restrict__ ws)
{
    const int lane = threadIdx.x;
    const int mt = blockIdx.x;   // 0..127
    const int bh = blockIdx.y;   // 0..7
    const int nq = blockIdx.z;   // 0..3
    const int e = lane & 31;
    const int hp = lane >> 5;

    union U4 { uint4 u; short8 s; };
    const uint4 zero4 = make_uint4(0, 0, 0, 0);

    U4 kf;
    kf.u = (hp == 0)
        ? *(const uint4*)(ws + K_OFF + ((size_t)bh * NSP + mt * 32 + e) * 16)
        : zero4;

    const uint4* qrows = (const uint4*)(ws + Q_OFF + (size_t)bh * NSP * 16);
    const uint4* vfr = (const uint4*)(ws + VF_OFF + (size_t)bh * 262144u);

    f32x16 acc = {};
    const f32x16 zc = {};

    const int nt0 = nq * 32;
    U4 qf_n, vf0_n, vf1_n;
    qf_n.u = (hp == 0) ? qrows[nt0 * 32 + e] : zero4;
    vf0_n.u = vfr[(nt0 * 2 + 0) * 64 + lane];
    vf1_n.u = vfr[(nt0 * 2 + 1) * 64 + lane];

    for (int t = 0; t < 32; ++t) {
        U4 qf = qf_n, vf0 = vf0_n, vf1 = vf1_n;
        if (t < 31) {  // software prefetch next tile
            const int nt = nt0 + t + 1;
            qf_n.u = (hp == 0) ? qrows[nt * 32 + e] : zero4;
            vf0_n.u = vfr[(nt * 2 + 0) * 64 + lane];
            vf1_n.u = vfr[(nt * 2 + 1) * 64 + lane];
        }

        // S^T[n,m]: lane holds col m, 16 rows n
        f32x16 S = __builtin_amdgcn_mfma_f32_32x32x16_bf16(qf.s, kf.s, zc, 0, 0, 0);

        // exp2 (k pre-scaled by log2e) + truncation-pack to bf16 (v_perm)
        unsigned Qd[8];
#pragma unroll
        for (int i = 0; i < 8; ++i) {
            const float a = fast_exp2(S[2 * i]);
            const float b2 = fast_exp2(S[2 * i + 1]);
            Qd[i] = pack2bf_tr(a, b2);
        }

        // xor-32 exchange: build A-layout frags (rows m, k=n)
        const int sA0 = hp ? Qd[0] : Qd[2];
        const int sA1 = hp ? Qd[1] : Qd[3];
        const int rA0 = __shfl_xor(sA0, 32, 64);
        const int rA1 = __shfl_xor(sA1, 32, 64);
        const int sB0 = hp ? Qd[4] : Qd[6];
        const int sB1 = hp ? Qd[5] : Qd[7];
        const int rB0 = __shfl_xor(sB0, 32, 64);
        const int rB1 = __shfl_xor(sB1, 32, 64);

        U4 f0, f1;
        f0.u = hp ? make_uint4(rA0, rA1, Qd[2], Qd[3])
                  : make_uint4(Qd[0], Qd[1], rA0, rA1);
        f1.u = hp ? make_uint4(rB0, rB1, Qd[6], Qd[7])
                  : make_uint4(Qd[4], Qd[5], rB0, rB1);

        acc = __builtin_amdgcn_mfma_f32_32x32x16_bf16(f0.s, vf0.s, acc, 0, 0, 0);
        acc = __builtin_amdgcn_mfma_f32_32x32x16_bf16(f1.s, vf1.s, acc, 0, 0, 0);
    }

    // store partial (cols e<=8: 8 o-channels + l at e=8), 4x float4 per lane
    if (e <= 8) {
        float* pp = (float*)(ws + P_OFF) +
                    ((((size_t)bh * 128 + mt) * 4 + nq) * 18 + hp * 9 + e) * 16;
        *(float4*)(pp + 0)  = make_float4(acc[0], acc[1], acc[2], acc[3]);
        *(float4*)(pp + 4)  = make_float4(acc[4], acc[5], acc[6], acc[7]);
        *(float4*)(pp + 8)  = make_float4(acc[8], acc[9], acc[10], acc[11]);
        *(float4*)(pp + 12) = make_float4(acc[12], acc[13], acc[14], acc[15]);
    }
}

// ---------------------------------------------------------------------------
// K3: epilogue. Sum 4 n-quarter partials, normalize, Wo+bias+gamma+residual.
// grid (32 mstrips, 8 bh), block 256.
// ---------------------------------------------------------------------------
__global__ __launch_bounds__(256) void attn_epilogue(
    const unsigned char* __restrict__ ws,
    const float* __restrict__ x,
    const float* __restrict__ Wo, const float* __restrict__ bo,
    const float* __restrict__ gamma,
    float* __restrict__ out)
{
    __shared__ float sO[128 * 13];
    const int tid = threadIdx.x;
    const int ms = blockIdx.x;   // 0..31
    const int bh = blockIdx.y;   // 0..7
    const int h = bh & (NH - 1);
    const int b = bh >> 2;

    const float* P = (const float*)(ws + P_OFF);
    for (int idx = tid; idx < 128 * 9; idx += 256) {
        const int m_l = idx / 9, e = idx % 9;
        const int mt = ms * 4 + (m_l >> 5);
        const int m32 = m_l & 31;
        const int hp = (m32 >> 2) & 1;
        const int r = (m32 & 3) + 4 * (m32 >> 3);
        const size_t base = ((((size_t)bh * 128 + mt) * 4) * 18 + hp * 9 + e) * 16 + r;
        const float s = P[base] + P[base + 18 * 16] +
                        P[base + 2 * 18 * 16] + P[base + 3 * 18 * 16];
        sO[m_l * 13 + e] = s;
    }
    __syncthreads();

    const int m_l = tid & 127;
    const int half = tid >> 7;
    const float rl = 1.0f / sO[m_l * 13 + 8];
    float od[DQK];
#pragma unroll
    for (int d = 0; d < DQK; ++d) od[d] = sO[m_l * 13 + d] * rl;

    const float g = gamma[h];
    const int mg = ms * 128 + m_l;
#pragma unroll
    for (int eo = half * 32; eo < half * 32 + 32; ++eo) {
        const float* wo = Wo + (h * ATH + eo) * DQK;
        float y = bo[h * ATH + eo];
#pragma unroll
        for (int d = 0; d < DQK; ++d) y = fmaf(wo[d], od[d], y);
        const size_t oi = ((size_t)(b * IN_DIM) + h * ATH + eo) * NSP + mg;
        out[oi] = fmaf(g, y, x[oi]);
    }
}

extern "C" void kernel_launch(void* const* d_in, const int* in_sizes, int n_in,
                              void* d_out, int out_size, void* d_ws, size_t ws_size,
                              hipStream_t stream)
{
    const float* x = (const float*)d_in[0];
    const float* Wq = (const float*)d_in[1];
    const float* bq = (const float*)d_in[2];
    const float* Wk = (const float*)d_in[3];
    const float* bk = (const float*)d_in[4];
    const float* Wv = (const float*)d_in[5];
    const float* bv = (const float*)d_in[6];
    const float* Wo = (const float*)d_in[7];
    const float* bo = (const float*)d_in[8];
    const float* gamma = (const float*)d_in[9];
    float* out = (float*)d_out;
    unsigned char* ws = (unsigned char*)d_ws;  // uses ~8 MB

    qkv_gemm<<<dim3(128, 3, NB), 64, 0, stream>>>(
        x, Wq, bq, Wk, bk, Wv, bv, ws);
    attn_partial<<<dim3(128, NB * NH, 4), 64, 0, stream>>>(ws);
    attn_epilogue<<<dim3(32, NB * NH), 256, 0, stream>>>(
        ws, x, Wo, bo, gamma, out);
}

// Round 6
// 106.837 us; speedup vs baseline: 2.4551x; 1.0985x over previous
//
#include <hip/hip_runtime.h>
#include <hip/hip_bf16.h>

#define IN_DIM 256
#define NH 4
#define DQK 8
#define ATH 64
#define NB 2
#define NSP 4096  // 64*64
#define LOG2E 1.44269504088896f

typedef __attribute__((ext_vector_type(8))) short short8;
typedef __attribute__((ext_vector_type(16))) float f32x16;

// ws byte layout:
//   Q_OFF : q rows bf16 [8 bh][4096 n][8d]                       512 KB
//   K_OFF : k rows bf16 [8 bh][4096 m][8d] (pre-scaled log2e)    512 KB
//   VF_OFF: v B-frags bf16 [8 bh][128 T][2 c2][64 lane][8j]      2 MB
//           (lane = 32*h2 + e; elem j -> n = 32T+16c2+8h2+j, col e; e=8 ones)
// NOTE (round-4 lesson): no cross-block fences/atomics — an all-blocks
// device-scope __threadfence() (buffer_wbl2) cost ~180 us. Cross-wave
// reduction happens at BLOCK scope in LDS; kernel boundary is the only
// device-wide release point.
#define Q_OFF 0u
#define K_OFF (512u * 1024u)
#define VF_OFF (1024u * 1024u)

__device__ __forceinline__ float fast_exp2(float x) {
#if __has_builtin(__builtin_amdgcn_exp2f)
    return __builtin_amdgcn_exp2f(x);
#else
    return exp2f(x);
#endif
}

// round-to-nearest-even fp32->bf16 (finite inputs only)
__device__ __forceinline__ unsigned bf_rne(float f) {
    unsigned u = __float_as_uint(f);
    u += 0x7FFFu + ((u >> 16) & 1u);
    return u >> 16;
}
__device__ __forceinline__ unsigned pack2bf(float a, float b) {
    return bf_rne(a) | (bf_rne(b) << 16);
}
// truncation pack (softmax P only: truncation bias cancels in P/sum(P)).
__device__ __forceinline__ unsigned pack2bf_tr(float a, float b) {
#if __has_builtin(__builtin_amdgcn_perm)
    return __builtin_amdgcn_perm(__float_as_uint(b), __float_as_uint(a), 0x07060302u);
#else
    return (__float_as_uint(a) >> 16) | (__float_as_uint(b) & 0xFFFF0000u);
#endif
}

// Register-half exchange: given per-lane a, b, produce
//   lo = { a(l) for l<32            | b(l-32) for l>=32 }
//   hi = { a(l+32) for l<32         | b(l)    for l>=32 }
// gfx950 v_permlane32_swap_b32 does exactly this in one instr per pair.
__device__ __forceinline__ void plswap(unsigned a, unsigned b,
                                       unsigned& lo, unsigned& hi)
{
#if __has_builtin(__builtin_amdgcn_permlane32_swap)
    auto r = __builtin_amdgcn_permlane32_swap(a, b, false, false);
    lo = r[0];
    hi = r[1];
#else
    const int hp = (threadIdx.x >> 5) & 1;
    const int s = hp ? (int)a : (int)b;
    const unsigned r0 = (unsigned)__shfl_xor(s, 32, 64);
    lo = hp ? r0 : a;
    hi = hp ? b : r0;
#endif
}

// ---------------------------------------------------------------------------
// K1: qkv as one MFMA GEMM. D[96,4096] = Wcat[96,256] x[256,4096] per b.
// Rows R: h = R/24, sel = (R%24)/8 (0=q,1=k,2=v), d = R%8.
// grid (128 n-tiles, 3 m-tiles, 2 b) = 768 waves, 16 MFMAs each.
// Epilogue: +bias, k*log2e, permlane32_swap repack. q/k stored as coalesced
// 16B rows; v scattered directly into PV B-frag layout (incl. ones col e=8).
// ---------------------------------------------------------------------------
__global__ __launch_bounds__(64) void qkv_gemm(
    const float* __restrict__ x,
    const float* __restrict__ Wq, const float* __restrict__ bq,
    const float* __restrict__ Wk, const float* __restrict__ bk,
    const float* __restrict__ Wv, const float* __restrict__ bv,
    unsigned char* __restrict__ ws)
{
    const int lane = threadIdx.x;
    const int nt = blockIdx.x;   // 0..127
    const int mt = blockIdx.y;   // 0..2
    const int b  = blockIdx.z;   // 0..1
    const int col = lane & 31;
    const int hp  = lane >> 5;

    // this lane's A-row of Wcat
    const int R = mt * 32 + col;
    const int h = R / 24;
    const int r24 = R % 24;
    const int sel = r24 >> 3;
    const int dd = r24 & 7;
    const float* Wsel = (sel == 0) ? Wq : (sel == 1) ? Wk : Wv;
    const float* wrow = Wsel + (h * DQK + dd) * IN_DIM;

    // x column base: c = kt*16 + hp*8 + j, n = nt*32 + col
    const float* xb = x + (size_t)b * IN_DIM * NSP + (size_t)(hp * 8) * NSP + nt * 32 + col;

    union U4 { uint4 u; short8 s; };
    f32x16 acc = {};

#pragma unroll
    for (int kt = 0; kt < 16; ++kt) {
        const float4 wa = *(const float4*)(wrow + kt * 16 + hp * 8);
        const float4 wb = *(const float4*)(wrow + kt * 16 + hp * 8 + 4);
        U4 af;
        af.u.x = pack2bf(wa.x, wa.y);
        af.u.y = pack2bf(wa.z, wa.w);
        af.u.z = pack2bf(wb.x, wb.y);
        af.u.w = pack2bf(wb.z, wb.w);

        float xv[8];
#pragma unroll
        for (int j = 0; j < 8; ++j) xv[j] = xb[(size_t)(kt * 16 + j) * NSP];
        U4 bfm;
        bfm.u.x = pack2bf(xv[0], xv[1]);
        bfm.u.y = pack2bf(xv[2], xv[3]);
        bfm.u.z = pack2bf(xv[4], xv[5]);
        bfm.u.w = pack2bf(xv[6], xv[7]);

        acc = __builtin_amdgcn_mfma_f32_32x32x16_bf16(af.s, bfm.s, acc, 0, 0, 0);
    }

    // epilogue: rows m = (reg&3) + 8*(reg>>2) + 4*hp. Row-group g (m=8g..8g+7)
    // = regs 4g..4g+3; one (h,sel) per group. Pair groups; permlane32_swap
    // assembles the full 8-d row: hp0 lanes hold gA's row, hp1 hold gB's.
    const int n = nt * 32 + col;
#pragma unroll
    for (int p = 0; p < 2; ++p) {
        const int gA = 2 * p, gB = 2 * p + 1;
        const int RA = mt * 32 + 8 * gA, RB = mt * 32 + 8 * gB;
        const int hA = RA / 24, hB = RB / 24;
        const int selA = (RA % 24) >> 3, selB = (RB % 24) >> 3;
        const float* bsA = (selA == 0) ? bq : (selA == 1) ? bk : bv;
        const float* bsB = (selB == 0) ? bq : (selB == 1) ? bk : bv;
        const float scA = (selA == 1) ? LOG2E : 1.0f;
        const float scB = (selB == 1) ? LOG2E : 1.0f;

        float vA[4], vB[4];
#pragma unroll
        for (int j = 0; j < 4; ++j) {
            vA[j] = (acc[4 * gA + j] + bsA[hA * DQK + 4 * hp + j]) * scA;
            vB[j] = (acc[4 * gB + j] + bsB[hB * DQK + 4 * hp + j]) * scB;
        }
        const unsigned PA0 = pack2bf(vA[0], vA[1]), PA1 = pack2bf(vA[2], vA[3]);
        const unsigned PB0 = pack2bf(vB[0], vB[1]), PB1 = pack2bf(vB[2], vB[3]);

        uint4 row;
        plswap(PA0, PB0, row.x, row.z);
        plswap(PA1, PB1, row.y, row.w);

        // this lane now holds the full row of group gX = (hp ? gB : gA)
        const int selX = hp ? selB : selA;
        const int hX = hp ? hB : hA;
        const int bhX = b * NH + hX;

        if (selX == 2) {
            // scatter v row into PV B-frag layout + ones col e=8
            unsigned char* dst = ws + VF_OFF + (size_t)bhX * 262144u +
                (size_t)((nt * 2 + ((col >> 4) & 1)) * 64 + 32 * ((col >> 3) & 1)) * 16 +
                (col & 7) * 2;
            *(unsigned short*)(dst + 0 * 16) = (unsigned short)(row.x);
            *(unsigned short*)(dst + 1 * 16) = (unsigned short)(row.x >> 16);
            *(unsigned short*)(dst + 2 * 16) = (unsigned short)(row.y);
            *(unsigned short*)(dst + 3 * 16) = (unsigned short)(row.y >> 16);
            *(unsigned short*)(dst + 4 * 16) = (unsigned short)(row.z);
            *(unsigned short*)(dst + 5 * 16) = (unsigned short)(row.z >> 16);
            *(unsigned short*)(dst + 6 * 16) = (unsigned short)(row.w);
            *(unsigned short*)(dst + 7 * 16) = (unsigned short)(row.w >> 16);
            *(unsigned short*)(dst + 8 * 16) = 0x3F80;  // bf16 1.0
        } else {
            unsigned char* d = ws + ((selX == 0) ? Q_OFF : K_OFF) +
                               ((size_t)bhX * NSP + n) * 16;
            *(uint4*)d = row;
        }
    }
}

// ---------------------------------------------------------------------------
// K2: MFMA flash attention (transposed softmax) with BLOCK-scope reduce +
// fused epilogue. grid (128 mt, 8 bh), block 256 = 4 waves; wave w streams
// n-quarter w. Main loop barrier/LDS-free per wave; partials meet in LDS
// (block scope, cheap), then Wo + bias + gamma + residual writeout.
// ---------------------------------------------------------------------------
__global__ __launch_bounds__(256, 4) void attn_block(
    unsigned char* __restrict__ ws,
    const float* __restrict__ x,
    const float* __restrict__ Wo, const float* __restrict__ bo,
    const float* __restrict__ gamma,
    float* __restrict__ out)
{
    const int tid = threadIdx.x;
    const int lane = tid & 63;
    const int w = tid >> 6;      // n-quarter 0..3
    const int mt = blockIdx.x;   // 0..127
    const int bh = blockIdx.y;   // 0..7
    const int e = lane & 31;
    const int hp = lane >> 5;

    union U4 { uint4 u; short8 s; };
    const uint4 zero4 = make_uint4(0, 0, 0, 0);

    U4 kf;
    kf.u = (hp == 0)
        ? *(const uint4*)(ws + K_OFF + ((size_t)bh * NSP + mt * 32 + e) * 16)
        : zero4;

    const uint4* qrows = (const uint4*)(ws + Q_OFF + (size_t)bh * NSP * 16);
    const uint4* vfr = (const uint4*)(ws + VF_OFF + (size_t)bh * 262144u);

    f32x16 acc = {};
    const f32x16 zc = {};

    const int nt0 = w * 32;
    U4 qf_n, vf0_n, vf1_n;
    qf_n.u = (hp == 0) ? qrows[nt0 * 32 + e] : zero4;
    vf0_n.u = vfr[(nt0 * 2 + 0) * 64 + lane];
    vf1_n.u = vfr[(nt0 * 2 + 1) * 64 + lane];

    for (int t = 0; t < 32; ++t) {
        U4 qf = qf_n, vf0 = vf0_n, vf1 = vf1_n;
        if (t < 31) {  // software prefetch next tile
            const int nt = nt0 + t + 1;
            qf_n.u = (hp == 0) ? qrows[nt * 32 + e] : zero4;
            vf0_n.u = vfr[(nt * 2 + 0) * 64 + lane];
            vf1_n.u = vfr[(nt * 2 + 1) * 64 + lane];
        }

        // S^T[n,m]: lane holds col m, 16 rows n
        f32x16 S = __builtin_amdgcn_mfma_f32_32x32x16_bf16(qf.s, kf.s, zc, 0, 0, 0);

        // exp2 (k pre-scaled by log2e) + truncation-pack to bf16 (v_perm)
        unsigned Qd[8];
#pragma unroll
        for (int i = 0; i < 8; ++i) {
            const float a = fast_exp2(S[2 * i]);
            const float b2 = fast_exp2(S[2 * i + 1]);
            Qd[i] = pack2bf_tr(a, b2);
        }

        // permlane32_swap: build A-layout frags (rows m, k=n) in 4 instrs
        U4 f0, f1;
        plswap(Qd[0], Qd[2], f0.u.x, f0.u.z);
        plswap(Qd[1], Qd[3], f0.u.y, f0.u.w);
        plswap(Qd[4], Qd[6], f1.u.x, f1.u.z);
        plswap(Qd[5], Qd[7], f1.u.y, f1.u.w);

        acc = __builtin_amdgcn_mfma_f32_32x32x16_bf16(f0.s, vf0.s, acc, 0, 0, 0);
        acc = __builtin_amdgcn_mfma_f32_32x32x16_bf16(f1.s, vf1.s, acc, 0, 0, 0);
    }

    // ---- block-scope reduce of the 4 n-quarter partials in LDS ----
    __shared__ float sP[4][18][16];  // [wave][hp*9+e][reg] = 4608 B
    __shared__ float sO[32 * 9];     // [m][e]

    if (e <= 8) {
        float* pp = &sP[w][hp * 9 + e][0];
        *(float4*)(pp + 0)  = make_float4(acc[0], acc[1], acc[2], acc[3]);
        *(float4*)(pp + 4)  = make_float4(acc[4], acc[5], acc[6], acc[7]);
        *(float4*)(pp + 8)  = make_float4(acc[8], acc[9], acc[10], acc[11]);
        *(float4*)(pp + 12) = make_float4(acc[12], acc[13], acc[14], acc[15]);
    }
    __syncthreads();

    for (int idx = tid; idx < 288; idx += 256) {
        const int slot = idx >> 4, r = idx & 15;
        const int hp2 = slot / 9, e2 = slot - hp2 * 9;
        const int m = (r & 3) + 8 * (r >> 2) + 4 * hp2;
        sO[m * 9 + e2] = sP[0][slot][r] + sP[1][slot][r] +
                         sP[2][slot][r] + sP[3][slot][r];
    }
    __syncthreads();

    // ---- epilogue: y = gamma*(Wo·(o/l)+bo) + x ----
    const int h = bh & (NH - 1);
    const int b = bh >> 2;
    const int m = tid & 31;
    const int grp = tid >> 5;    // 0..7, 8 out-channels each
    const float rl = 1.0f / sO[m * 9 + 8];
    float od[DQK];
#pragma unroll
    for (int d = 0; d < DQK; ++d) od[d] = sO[m * 9 + d] * rl;

    const float g = gamma[h];
    const int mg = mt * 32 + m;
#pragma unroll
    for (int i = 0; i < 8; ++i) {
        const int eo = grp * 8 + i;
        const float* wo = Wo + (h * ATH + eo) * DQK;
        const float4 w0 = *(const float4*)(wo);
        const float4 w1 = *(const float4*)(wo + 4);
        float y = bo[h * ATH + eo];
        y = fmaf(w0.x, od[0], y); y = fmaf(w0.y, od[1], y);
        y = fmaf(w0.z, od[2], y); y = fmaf(w0.w, od[3], y);
        y = fmaf(w1.x, od[4], y); y = fmaf(w1.y, od[5], y);
        y = fmaf(w1.z, od[6], y); y = fmaf(w1.w, od[7], y);
        const size_t oi = ((size_t)(b * IN_DIM) + h * ATH + eo) * NSP + mg;
        out[oi] = fmaf(g, y, x[oi]);
    }
}

extern "C" void kernel_launch(void* const* d_in, const int* in_sizes, int n_in,
                              void* d_out, int out_size, void* d_ws, size_t ws_size,
                              hipStream_t stream)
{
    const float* x = (const float*)d_in[0];
    const float* Wq = (const float*)d_in[1];
    const float* bq = (const float*)d_in[2];
    const float* Wk = (const float*)d_in[3];
    const float* bk = (const float*)d_in[4];
    const float* Wv = (const float*)d_in[5];
    const float* bv = (const float*)d_in[6];
    const float* Wo = (const float*)d_in[7];
    const float* bo = (const float*)d_in[8];
    const float* gamma = (const float*)d_in[9];
    float* out = (float*)d_out;
    unsigned char* ws = (unsigned char*)d_ws;  // uses ~3 MB

    qkv_gemm<<<dim3(128, 3, NB), 64, 0, stream>>>(
        x, Wq, bq, Wk, bk, Wv, bv, ws);
    attn_block<<<dim3(128, NB * NH), 256, 0, stream>>>(
        ws, x, Wo, bo, gamma, out);
}